// Round 4
// baseline (393.081 us; speedup 1.0000x reference)
//
#include <hip/hip_runtime.h>
#include <hip/hip_bf16.h>
#include <cstdint>

#define NUM_TOKENS 8192
#define IN_DIM 4096
#define OUT_DIM 4096
#define NUM_AD 8
#define RANK 64
#define RTOT (NUM_AD * RANK)           // 512
#define KAUG (IN_DIM + RTOT)           // 4608

typedef __bf16 bf16x8 __attribute__((ext_vector_type(8)));
typedef float f32x4 __attribute__((ext_vector_type(4)));
typedef float f32x16 __attribute__((ext_vector_type(16)));
typedef unsigned short ushort_t;

__device__ __forceinline__ unsigned f2bf_u(float f) {
  unsigned u = __float_as_uint(f);
  return (u + 0x7FFFu + ((u >> 16) & 1u)) >> 16;   // round-to-nearest-even
}
__device__ __forceinline__ uint2 pack4(float4 v) {
  uint2 r;
  r.x = f2bf_u(v.x) | (f2bf_u(v.y) << 16);
  r.y = f2bf_u(v.z) | (f2bf_u(v.w) << 16);
  return r;
}

// [R][4096] f32 -> [R][KAUG] bf16 (cols 0..4095). Used for x and weight.
__global__ void k_cvt_pad(const float* __restrict__ src, ushort_t* __restrict__ dst) {
  int i = blockIdx.x * blockDim.x + threadIdx.x;
  int idx = i << 2;
  int row = idx / IN_DIM;
  int col = idx - row * IN_DIM;
  float4 v = *reinterpret_cast<const float4*>(src + idx);
  *reinterpret_cast<uint2*>(dst + row * KAUG + col) = pack4(v);
}

// A_buffer [8][64][4096] f32 -> flat [512][4096] bf16
__global__ void k_cvt_flat(const float* __restrict__ src, ushort_t* __restrict__ dst) {
  int i = blockIdx.x * blockDim.x + threadIdx.x;
  int idx = i << 2;
  float4 v = *reinterpret_cast<const float4*>(src + idx);
  *reinterpret_cast<uint2*>(dst + idx) = pack4(v);
}

// B_buffer [8][4096][64] f32 -> Waug[o][4096 + a*64 + r] bf16
__global__ void k_cvt_b(const float* __restrict__ src, ushort_t* __restrict__ dst) {
  int i = blockIdx.x * blockDim.x + threadIdx.x;
  int idx = i << 2;
  int a = idx / (OUT_DIM * RANK);
  int rem = idx - a * (OUT_DIM * RANK);
  int o = rem / RANK;
  int r = rem - o * RANK;
  float4 v = *reinterpret_cast<const float4*>(src + idx);
  *reinterpret_cast<uint2*>(dst + o * KAUG + IN_DIM + a * RANK + r) = pack4(v);
}

#define AS1(p) (const __attribute__((address_space(1))) void*)(p)
#define AS3(p) (__attribute__((address_space(3))) void*)(p)
#define GLD(gp, lp) __builtin_amdgcn_global_load_lds(AS1(gp), AS3(lp), 16, 0, 0)

// ---------- LoRA-A GEMM: 128x64 tile, 4 waves, BK=32, high occupancy ----------
// Z[t*KAUG + IN_DIM + n] = (n>>6 == aid[t]) ? bf16(acc) : 0
// C[8192,512] = Xaug[8192, : 4096 (stride KAUG)] x Abf[512,4096]^T
__global__ __launch_bounds__(256)
void gemm_lora_a(const ushort_t* __restrict__ A, const ushort_t* __restrict__ B,
                 ushort_t* __restrict__ Z, const int* __restrict__ aid) {
  constexpr int BK = 32;
  __shared__ __align__(16) ushort_t As[128 * BK];   // 8 KB
  __shared__ __align__(16) ushort_t Bs[64 * BK];    // 4 KB

  const int tid = threadIdx.x;
  const int w = tid >> 6;
  const int l = tid & 63;
  const int wr = w >> 1, wc = w & 1;      // wave grid 2Mx2N; per-wave 64x32

  const int bid = blockIdx.x;             // nwg = 64*8 = 512, cpx = 64
  const int swz = (bid & 7) * 64 + (bid >> 3);
  const int by = swz >> 3, bx = swz & 7;
  const int brow = by << 7, bcol = bx << 6;

  const ushort_t* ga = A + (size_t)(brow + (tid >> 2)) * KAUG + ((tid & 3) << 3);
  const ushort_t* gb = B + (size_t)(bcol + (tid >> 2)) * IN_DIM + ((tid & 3) << 3);
  ushort_t* sa = As + w * 512;
  ushort_t* sb = Bs + w * 512;
  const size_t ga2 = (size_t)64 * KAUG;

  const int lr = l & 15;
  const int lkb = (l >> 4) << 3;
  const ushort_t* fa = As + (wr * 64 + lr) * BK + lkb;
  const ushort_t* fb = Bs + (wc * 32 + lr) * BK + lkb;

  f32x4 acc[4][2] = {};

  for (int k0 = 0; k0 < IN_DIM; k0 += BK) {
    GLD(ga + k0, sa);
    GLD(ga + k0 + ga2, sa + 2048);
    GLD(gb + k0, sb);
    __syncthreads();
    bf16x8 av[4], bv[2];
#pragma unroll
    for (int mb = 0; mb < 4; ++mb)
      av[mb] = *reinterpret_cast<const bf16x8*>(fa + mb * 16 * BK);
#pragma unroll
    for (int nb = 0; nb < 2; ++nb)
      bv[nb] = *reinterpret_cast<const bf16x8*>(fb + nb * 16 * BK);
#pragma unroll
    for (int mb = 0; mb < 4; ++mb)
#pragma unroll
      for (int nb = 0; nb < 2; ++nb)
        acc[mb][nb] = __builtin_amdgcn_mfma_f32_16x16x32_bf16(av[mb], bv[nb], acc[mb][nb], 0, 0, 0);
    __syncthreads();
  }

  const int orow = brow + wr * 64 + ((l >> 4) << 2);
#pragma unroll
  for (int mb = 0; mb < 4; ++mb) {
#pragma unroll
    for (int j = 0; j < 4; ++j) {
      int t = orow + mb * 16 + j;
      int ad = aid[t];
#pragma unroll
      for (int nb = 0; nb < 2; ++nb) {
        int cc = bcol + wc * 32 + nb * 16 + lr;
        float v = ((cc >> 6) == ad) ? acc[mb][nb][j] : 0.f;
        Z[(size_t)t * KAUG + IN_DIM + cc] = (ushort_t)f2bf_u(v);
      }
    }
  }
}

// ---------- 256^2-tile sparse-barrier counted-vmcnt GEMM, 32x32x16 MFMA ----------
// C[M,N] = A[M,K](lda) x B[N,K](ldb)^T + bias.  M,N % 256 == 0, K % 128 == 0.
// 8 waves (2Mx4N), per-wave C = 128x64 (4 mb x 2 nb of 32x32). LDS 128KB:
// 2 bufs x (A:2x16KB | B:2x16KB). Schedule identical to R3 (race-free ledger):
// 2 barriers + 2 vmcnt(4) per K-tile; B-frags register-pipelined (late LDBH).
// T2 read-swizzle: byte ^= ((row&7)<<4); source pre-swizzled (same involution).
__global__ __launch_bounds__(512, 2)
void gemm8(const ushort_t* __restrict__ A, int lda,
           const ushort_t* __restrict__ B, int ldb,
           int M, int N, int K,
           float* __restrict__ out, const float* __restrict__ bias) {
  extern __shared__ char lds[];
  const int tid = threadIdx.x;
  const int l = tid & 63;
  const int w = tid >> 6;       // 0..7
  const int wr = w >> 2;        // 0..1  (A-half / M-half ownership)
  const int wc = w & 3;         // 0..3  (N ownership: B-half wc>>1, 64-col slice wc&1)

  const int nbx = N >> 8;
  const int nwg = nbx * (M >> 8);
  const int cpx = nwg >> 3;     // nwg % 8 == 0 for all our launches
  const int bid = blockIdx.x;
  const int swz = (bid & 7) * cpx + (bid >> 3);
  const int by = swz / nbx, bx = swz - by * nbx;
  const int brow = by << 8, bcol = bx << 8;

  // stage-side constants (thread t writes LDS linear bytes j*8192 + t*16,
  // i.e. row j*64 + (t>>3), byte-in-row (t&7)*16; source col pre-swizzled)
  const int r0 = tid >> 3;                        // 0..63
  const int kc = ((tid & 7) ^ (r0 & 7)) << 3;     // element col, same involution as read

  // read-side constants (32x32x16 fragments)
  const int l31 = l & 31;
  const int lxor = (l & 7) << 4;                  // (row&7)<<4
  const int kb0 = (l >> 5) << 4;                  // 0 or 16 bytes (k-half per lane group)

  const int NT = K >> 6;         // K-tiles (even)
  const int NIT = NT >> 1;

  // stage one half-tile (2 x global_load_lds). buf = kt&1.
#define STG(mat, ld, rowbase, kt_, half, isB) do {                                   \
    int kt = (kt_); if (kt >= NT) kt -= NT;                                          \
    char* lb = lds + (((kt & 1) << 16) | ((isB) << 15) | ((half) << 14) | (w << 10));\
    const ushort_t* sp = (mat) + (size_t)((rowbase) + ((half) << 7) + r0) * (ld)     \
                         + (kt << 6) + kc;                                           \
    GLD(sp, lb);                                                                     \
    GLD(sp + 64 * (ld), lb + 8192);                                                  \
  } while (0)

  // A frag: row = mb*32 + (l&31) in wave's 128-row half; k-bytes ks*32 + kb0
#define LDA32(c, mb, ks)                                                             \
  (const bf16x8*)(lds + (((c) << 16) | (wr << 14))                                   \
                  + ((mb) * 32 + l31) * 128 + ((((ks) << 5) | kb0) ^ lxor))
  // B frag: row = (wc&1)*64 + nb*32 + (l&31) in B-half (wc>>1)
#define LDB32(c, nb, ks)                                                             \
  (const bf16x8*)(lds + (((c) << 16) | 32768 | ((wc >> 1) << 14))                    \
                  + (((wc & 1) * 64 + (nb) * 32 + l31) * 128) + ((((ks) << 5) | kb0) ^ lxor))

  f32x16 acc[4][2] = {};
  bf16x8 bfr[2][4];   // B-frags [nb][ks] for CURRENT tile; reloaded for next tile
                      // at the end of each tile's second region (WAR-ordered).

#define LDBH(c, nb) do {                                                             \
    _Pragma("unroll") for (int ks = 0; ks < 4; ++ks)                                 \
      bfr[nb][ks] = *LDB32(c, nb, ks);                                               \
  } while (0)

#define MFMAQ(q, a_)                                                                 \
    _Pragma("unroll") for (int ks = 0; ks < 4; ++ks)                                 \
      _Pragma("unroll") for (int nb = 0; nb < 2; ++nb)                               \
        acc[q][nb] = __builtin_amdgcn_mfma_f32_32x32x16_bf16(                        \
            a_[ks], bfr[nb][ks], acc[q][nb], 0, 0, 0)

  // prologue: T0 A+B complete, T1.B in flight; B(0)->bfr in registers
  STG(A, lda, brow, 0, 0, 0);
  STG(A, lda, brow, 0, 1, 0);
  STG(B, ldb, bcol, 0, 0, 1);
  STG(B, ldb, bcol, 0, 1, 1);
  STG(B, ldb, bcol, 1, 0, 1);
  STG(B, ldb, bcol, 1, 1, 1);
  asm volatile("s_waitcnt vmcnt(4)" ::: "memory");
  __builtin_amdgcn_s_barrier();
  __builtin_amdgcn_sched_barrier(0);
  LDBH(0, 0);
  LDBH(0, 1);

  // one K-tile: region01 {A-reads mb0,1 | stage A(T+1) | MFMA mb0,1 | vmcnt(4) bar}
  //             region23 {A-reads mb2,3 | stage B(T+2) | MFMA mb2,3 |
  //                       late-load bfr <- B(T+1) | vmcnt(4) bar}
#define TILE(c, TA, TB) do {                                                         \
    {                                                                                \
      bf16x8 a0[4], a1[4];                                                           \
      _Pragma("unroll") for (int ks = 0; ks < 4; ++ks) {                             \
        a0[ks] = *LDA32(c, 0, ks);                                                   \
        a1[ks] = *LDA32(c, 1, ks);                                                   \
      }                                                                              \
      STG(A, lda, brow, TA, 0, 0);                                                   \
      STG(A, lda, brow, TA, 1, 0);                                                   \
      __builtin_amdgcn_s_setprio(1);                                                 \
      MFMAQ(0, a0);                                                                  \
      MFMAQ(1, a1);                                                                  \
      __builtin_amdgcn_s_setprio(0);                                                 \
      asm volatile("s_waitcnt vmcnt(4)" ::: "memory");                               \
      __builtin_amdgcn_s_barrier();                                                  \
      __builtin_amdgcn_sched_barrier(0);                                             \
    }                                                                                \
    {                                                                                \
      bf16x8 a0[4], a1[4];                                                           \
      _Pragma("unroll") for (int ks = 0; ks < 4; ++ks) {                             \
        a0[ks] = *LDA32(c, 2, ks);                                                   \
        a1[ks] = *LDA32(c, 3, ks);                                                   \
      }                                                                              \
      STG(B, ldb, bcol, TB, 0, 1);                                                   \
      STG(B, ldb, bcol, TB, 1, 1);                                                   \
      __builtin_amdgcn_s_setprio(1);                                                 \
      MFMAQ(2, a0);                                                                  \
      MFMAQ(3, a1);                                                                  \
      __builtin_amdgcn_s_setprio(0);                                                 \
      LDBH((c) ^ 1, 0);                                                              \
      LDBH((c) ^ 1, 1);                                                              \
      asm volatile("s_waitcnt vmcnt(4)" ::: "memory");                               \
      __builtin_amdgcn_s_barrier();                                                  \
      __builtin_amdgcn_sched_barrier(0);                                             \
    }                                                                                \
  } while (0)

  for (int it = 0; it < NIT; ++it) {
    const int T = it << 1;
    TILE(0, T + 1, T + 2);
    TILE(1, T + 2, T + 3);
  }

  // epilogue: 32x32 D layout (m74/m101): col = l&31, row = (r&3) + 8*(r>>2) + 4*(l>>5)
  const int orow = brow + (wr << 7);
  const int rh = (l >> 5) << 2;
  const int ocb = bcol + (wc << 6) + l31;
  float bb[2];
#pragma unroll
  for (int nb = 0; nb < 2; ++nb) bb[nb] = bias[ocb + (nb << 5)];
#pragma unroll
  for (int mb = 0; mb < 4; ++mb)
#pragma unroll
    for (int nb = 0; nb < 2; ++nb)
#pragma unroll
      for (int r = 0; r < 16; ++r) {
        int row = orow + mb * 32 + (r & 3) + ((r >> 2) << 3) + rh;
        out[(size_t)row * N + ocb + (nb << 5)] = acc[mb][nb][r] + bb[nb];
      }
}

extern "C" void kernel_launch(void* const* d_in, const int* in_sizes, int n_in,
                              void* d_out, int out_size, void* d_ws, size_t ws_size,
                              hipStream_t stream) {
  const float* x    = (const float*)d_in[0];
  const float* wgt  = (const float*)d_in[1];
  const float* bias = (const float*)d_in[2];
  const float* Abuf = (const float*)d_in[3];
  const float* Bbuf = (const float*)d_in[4];
  const int*   aid  = (const int*)d_in[5];
  float* out = (float*)d_out;

  // workspace: Xaug[8192][4608] | Waug[4096][4608] | Abf[512][4096]  (bf16 as ushort)
  ushort_t* Xaug = (ushort_t*)d_ws;
  ushort_t* Waug = Xaug + (size_t)NUM_TOKENS * KAUG;
  ushort_t* Abf  = Waug + (size_t)OUT_DIM * KAUG;

  k_cvt_pad<<<NUM_TOKENS * (IN_DIM / 4) / 256, 256, 0, stream>>>(x, Xaug);
  k_cvt_pad<<<OUT_DIM * (IN_DIM / 4) / 256, 256, 0, stream>>>(wgt, Waug);
  k_cvt_b<<<NUM_AD * OUT_DIM * (RANK / 4) / 256, 256, 0, stream>>>(Bbuf, Waug);
  k_cvt_flat<<<RTOT * (IN_DIM / 4) / 256, 256, 0, stream>>>(Abuf, Abf);

  // Z = mask(X @ A_flat^T) into Xaug cols 4096..4607: M=8192 N=512 K=4096
  gemm_lora_a<<<(NUM_TOKENS / 128) * (RTOT / 64), 256, 0, stream>>>(Xaug, Abf, Xaug, aid);

  // out = Xaug @ Waug^T + bias: M=8192 N=4096 K=4608 (72 K-tiles, 36 iters)
  gemm8<<<(NUM_TOKENS / 256) * (OUT_DIM / 256), 512, 131072, stream>>>(
      Xaug, KAUG, Waug, KAUG, NUM_TOKENS, OUT_DIM, KAUG, out, bias);
}

// Round 5
// 354.748 us; speedup vs baseline: 1.1081x; 1.1081x over previous
//
#include <hip/hip_runtime.h>
#include <hip/hip_bf16.h>
#include <cstdint>

#define NUM_TOKENS 8192
#define IN_DIM 4096
#define OUT_DIM 4096
#define NUM_AD 8
#define RANK 64
#define RTOT (NUM_AD * RANK)           // 512
#define KAUG (IN_DIM + RTOT)           // 4608

typedef __bf16 bf16x8 __attribute__((ext_vector_type(8)));
typedef float f32x4 __attribute__((ext_vector_type(4)));
typedef unsigned short ushort_t;

__device__ __forceinline__ unsigned f2bf_u(float f) {
  unsigned u = __float_as_uint(f);
  return (u + 0x7FFFu + ((u >> 16) & 1u)) >> 16;   // round-to-nearest-even
}
__device__ __forceinline__ uint2 pack4(float4 v) {
  uint2 r;
  r.x = f2bf_u(v.x) | (f2bf_u(v.y) << 16);
  r.y = f2bf_u(v.z) | (f2bf_u(v.w) << 16);
  return r;
}

// Merged pad-convert: x [8192][4096] -> Xaug cols 0..4095, wgt [4096][4096] -> Waug.
// One thread = 4 elems. x-range: first 8388608 threads; wgt-range: next 4194304.
#define XTHREADS (NUM_TOKENS * IN_DIM / 4)
__global__ void k_cvt_pad2(const float* __restrict__ x, const float* __restrict__ wgt,
                           ushort_t* __restrict__ Xaug, ushort_t* __restrict__ Waug) {
  int i = blockIdx.x * blockDim.x + threadIdx.x;
  const float* src;
  ushort_t* dst;
  int idx;
  if (i < XTHREADS) {
    idx = i << 2;  src = x;  dst = Xaug;
  } else {
    idx = (i - XTHREADS) << 2;  src = wgt;  dst = Waug;
  }
  int row = idx / IN_DIM;
  int col = idx - row * IN_DIM;
  float4 v = *reinterpret_cast<const float4*>(src + idx);
  *reinterpret_cast<uint2*>(dst + (size_t)row * KAUG + col) = pack4(v);
}

// Merged small converts: A_buffer [8][64][4096] -> Abf flat [512][4096];
// B_buffer [8][4096][64] -> Waug[o][4096 + a*64 + r].
#define FTHREADS (RTOT * IN_DIM / 4)
__global__ void k_cvt_small(const float* __restrict__ Abuf, const float* __restrict__ Bbuf,
                            ushort_t* __restrict__ Abf, ushort_t* __restrict__ Waug) {
  int i = blockIdx.x * blockDim.x + threadIdx.x;
  if (i < FTHREADS) {
    int idx = i << 2;
    float4 v = *reinterpret_cast<const float4*>(Abuf + idx);
    *reinterpret_cast<uint2*>(Abf + idx) = pack4(v);
  } else {
    int idx = (i - FTHREADS) << 2;
    int a = idx / (OUT_DIM * RANK);
    int rem = idx - a * (OUT_DIM * RANK);
    int o = rem / RANK;
    int r = rem - o * RANK;
    float4 v = *reinterpret_cast<const float4*>(Bbuf + idx);
    *reinterpret_cast<uint2*>(Waug + (size_t)o * KAUG + IN_DIM + a * RANK + r) = pack4(v);
  }
}

#define AS1(p) (const __attribute__((address_space(1))) void*)(p)
#define AS3(p) (__attribute__((address_space(3))) void*)(p)
#define GLD(gp, lp) __builtin_amdgcn_global_load_lds(AS1(gp), AS3(lp), 16, 0, 0)

// ---------- LoRA-A GEMM: 128x64 tile, 4 waves, BK=32, high occupancy ----------
// Z[t*KAUG + IN_DIM + n] = (n>>6 == aid[t]) ? bf16(acc) : 0
__global__ __launch_bounds__(256)
void gemm_lora_a(const ushort_t* __restrict__ A, const ushort_t* __restrict__ B,
                 ushort_t* __restrict__ Z, const int* __restrict__ aid) {
  constexpr int BK = 32;
  __shared__ __align__(16) ushort_t As[128 * BK];   // 8 KB
  __shared__ __align__(16) ushort_t Bs[64 * BK];    // 4 KB

  const int tid = threadIdx.x;
  const int w = tid >> 6;
  const int l = tid & 63;
  const int wr = w >> 1, wc = w & 1;      // wave grid 2Mx2N; per-wave 64x32

  const int bid = blockIdx.x;             // nwg = 64*8 = 512, cpx = 64
  const int swz = (bid & 7) * 64 + (bid >> 3);
  const int by = swz >> 3, bx = swz & 7;
  const int brow = by << 7, bcol = bx << 6;

  const ushort_t* ga = A + (size_t)(brow + (tid >> 2)) * KAUG + ((tid & 3) << 3);
  const ushort_t* gb = B + (size_t)(bcol + (tid >> 2)) * IN_DIM + ((tid & 3) << 3);
  ushort_t* sa = As + w * 512;
  ushort_t* sb = Bs + w * 512;
  const size_t ga2 = (size_t)64 * KAUG;

  const int lr = l & 15;
  const int lkb = (l >> 4) << 3;
  const ushort_t* fa = As + (wr * 64 + lr) * BK + lkb;
  const ushort_t* fb = Bs + (wc * 32 + lr) * BK + lkb;

  f32x4 acc[4][2] = {};

  for (int k0 = 0; k0 < IN_DIM; k0 += BK) {
    GLD(ga + k0, sa);
    GLD(ga + k0 + ga2, sa + 2048);
    GLD(gb + k0, sb);
    __syncthreads();
    bf16x8 av[4], bv[2];
#pragma unroll
    for (int mb = 0; mb < 4; ++mb)
      av[mb] = *reinterpret_cast<const bf16x8*>(fa + mb * 16 * BK);
#pragma unroll
    for (int nb = 0; nb < 2; ++nb)
      bv[nb] = *reinterpret_cast<const bf16x8*>(fb + nb * 16 * BK);
#pragma unroll
    for (int mb = 0; mb < 4; ++mb)
#pragma unroll
      for (int nb = 0; nb < 2; ++nb)
        acc[mb][nb] = __builtin_amdgcn_mfma_f32_16x16x32_bf16(av[mb], bv[nb], acc[mb][nb], 0, 0, 0);
    __syncthreads();
  }

  const int orow = brow + wr * 64 + ((l >> 4) << 2);
#pragma unroll
  for (int mb = 0; mb < 4; ++mb) {
#pragma unroll
    for (int j = 0; j < 4; ++j) {
      int t = orow + mb * 16 + j;
      int ad = aid[t];
#pragma unroll
      for (int nb = 0; nb < 2; ++nb) {
        int cc = bcol + wc * 32 + nb * 16 + lr;
        float v = ((cc >> 6) == ad) ? acc[mb][nb][j] : 0.f;
        Z[(size_t)t * KAUG + IN_DIM + cc] = (ushort_t)f2bf_u(v);
      }
    }
  }
}

// ---------- 256^2-tile sparse-barrier counted-vmcnt GEMM (R3-exact, 16x16x32) ----------
// C[M,N] = A[M,K](lda) x B[N,K](ldb)^T + bias.  M,N % 256 == 0, K % 128 == 0.
// 8 waves (2Mx4N), per-wave C = 128x64. LDS 128KB: 2 bufs x (A:2x16KB | B:2x16KB).
// 2 barriers + 2 vmcnt(4) per K-tile. B-frags register-pipelined (late LDBH).
// T2 read-swizzle: byte ^= ((row&7)<<4); source pre-swizzled (same involution).
// NOTE R4 lesson: 32x32x16 fragment reads here trip 2.8e7 LDS bank conflicts
// (mechanism unexplained by octet-phase model) — keep 16x16x32, measured 0.
__global__ __launch_bounds__(512, 2)
void gemm8(const ushort_t* __restrict__ A, int lda,
           const ushort_t* __restrict__ B, int ldb,
           int M, int N, int K,
           float* __restrict__ out, const float* __restrict__ bias) {
  extern __shared__ char lds[];
  const int tid = threadIdx.x;
  const int l = tid & 63;
  const int w = tid >> 6;       // 0..7
  const int wr = w >> 2;        // 0..1  (A-half / M-half ownership)
  const int wc = w & 3;         // 0..3  (N ownership: B-half wc>>1, 64-col slice wc&1)

  const int nbx = N >> 8;
  const int nwg = nbx * (M >> 8);
  const int cpx = nwg >> 3;     // nwg % 8 == 0 for all our launches
  const int bid = blockIdx.x;
  const int swz = (bid & 7) * cpx + (bid >> 3);
  const int by = swz / nbx, bx = swz - by * nbx;
  const int brow = by << 8, bcol = bx << 8;

  // stage-side constants (thread t writes LDS linear bytes j*8192 + t*16,
  // i.e. row j*64 + (t>>3), byte-in-row (t&7)*16; source col pre-swizzled)
  const int r0 = tid >> 3;                        // 0..63
  const int kc = ((tid & 7) ^ (r0 & 7)) << 3;     // element col, same involution as read

  // read-side constants
  const int lr = l & 15;
  const int lxor = (l & 7) << 4;                  // (row&7)<<4
  const int kb0 = (l >> 4) << 4;                  // 0,16,32,48 bytes

  const int NT = K >> 6;         // K-tiles (even)
  const int NIT = NT >> 1;

  // stage one half-tile (2 x global_load_lds). buf = kt&1.
#define STG(mat, ld, rowbase, kt_, half, isB) do {                                   \
    int kt = (kt_); if (kt >= NT) kt -= NT;                                          \
    char* lb = lds + (((kt & 1) << 16) | ((isB) << 15) | ((half) << 14) | (w << 10));\
    const ushort_t* sp = (mat) + (size_t)((rowbase) + ((half) << 7) + r0) * (ld)     \
                         + (kt << 6) + kc;                                           \
    GLD(sp, lb);                                                                     \
    GLD(sp + 64 * (ld), lb + 8192);                                                  \
  } while (0)

#define LDA_ADDR(c, q, m, ks)                                                        \
  (const bf16x8*)(lds + (((c) << 16) | (wr << 14))                                   \
                  + ((q) * 32 + (m) * 16 + lr) * 128 + ((((ks) << 6) | kb0) ^ lxor))
#define LDB_ADDR(c, n, ks)                                                           \
  (const bf16x8*)(lds + (((c) << 16) | 32768 | ((wc >> 1) << 14))                    \
                  + (((wc & 1) << 6) + (n) * 16 + lr) * 128 + ((((ks) << 6) | kb0) ^ lxor))

  f32x4 acc[8][4] = {};
  bf16x8 bfr[4][2];   // B-frags for the CURRENT tile; reloaded (next tile) at
                      // the end of each tile's second region (WAR-ordered).

#define LDBH(c, h, dst) do {                                                         \
    _Pragma("unroll") for (int n = 2 * (h); n < 2 * (h) + 2; ++n)                    \
      _Pragma("unroll") for (int ks = 0; ks < 2; ++ks)                               \
        dst[n][ks] = *LDB_ADDR(c, n, ks);                                            \
  } while (0)

#define MFMAQ(q, a_, bfr_)                                                           \
    _Pragma("unroll") for (int ks = 0; ks < 2; ++ks)                                 \
      _Pragma("unroll") for (int m = 0; m < 2; ++m)                                  \
        _Pragma("unroll") for (int n = 0; n < 4; ++n)                                \
          acc[2 * (q) + m][n] = __builtin_amdgcn_mfma_f32_16x16x32_bf16(             \
              a_[m][ks], bfr_[n][ks], acc[2 * (q) + m][n], 0, 0, 0)

  // prologue: T0 A+B complete, T1.B in flight; B(0)->bfr in registers
  STG(A, lda, brow, 0, 0, 0);
  STG(A, lda, brow, 0, 1, 0);
  STG(B, ldb, bcol, 0, 0, 1);
  STG(B, ldb, bcol, 0, 1, 1);
  STG(B, ldb, bcol, 1, 0, 1);
  STG(B, ldb, bcol, 1, 1, 1);
  asm volatile("s_waitcnt vmcnt(4)" ::: "memory");
  __builtin_amdgcn_s_barrier();
  __builtin_amdgcn_sched_barrier(0);
  LDBH(0, 0, bfr);
  LDBH(0, 1, bfr);

  // one K-tile: region01 {A-reads q0,q1 | stage A(T+1) | MFMA q0,q1 | vmcnt(4) bar}
  //             region23 {A-reads q2,q3 | stage B(T+2) | MFMA q2,q3 |
  //                       late-load bfr <- B(T+1) | vmcnt(4) bar}
#define TILE(c, TA, TB) do {                                                         \
    {                                                                                \
      bf16x8 a0[2][2], a1[2][2];                                                     \
      _Pragma("unroll") for (int m = 0; m < 2; ++m)                                  \
        _Pragma("unroll") for (int ks = 0; ks < 2; ++ks) {                           \
          a0[m][ks] = *LDA_ADDR(c, 0, m, ks);                                        \
          a1[m][ks] = *LDA_ADDR(c, 1, m, ks);                                        \
        }                                                                            \
      STG(A, lda, brow, TA, 0, 0);                                                   \
      STG(A, lda, brow, TA, 1, 0);                                                   \
      __builtin_amdgcn_s_setprio(1);                                                 \
      MFMAQ(0, a0, bfr);                                                             \
      MFMAQ(1, a1, bfr);                                                             \
      __builtin_amdgcn_s_setprio(0);                                                 \
      asm volatile("s_waitcnt vmcnt(4)" ::: "memory");                               \
      __builtin_amdgcn_s_barrier();                                                  \
      __builtin_amdgcn_sched_barrier(0);                                             \
    }                                                                                \
    {                                                                                \
      bf16x8 a0[2][2], a1[2][2];                                                     \
      _Pragma("unroll") for (int m = 0; m < 2; ++m)                                  \
        _Pragma("unroll") for (int ks = 0; ks < 2; ++ks) {                           \
          a0[m][ks] = *LDA_ADDR(c, 2, m, ks);                                        \
          a1[m][ks] = *LDA_ADDR(c, 3, m, ks);                                        \
        }                                                                            \
      STG(B, ldb, bcol, TB, 0, 1);                                                   \
      STG(B, ldb, bcol, TB, 1, 1);                                                   \
      __builtin_amdgcn_s_setprio(1);                                                 \
      MFMAQ(2, a0, bfr);                                                             \
      MFMAQ(3, a1, bfr);                                                             \
      __builtin_amdgcn_s_setprio(0);                                                 \
      LDBH((c) ^ 1, 0, bfr);                                                         \
      LDBH((c) ^ 1, 1, bfr);                                                         \
      asm volatile("s_waitcnt vmcnt(4)" ::: "memory");                               \
      __builtin_amdgcn_s_barrier();                                                  \
      __builtin_amdgcn_sched_barrier(0);                                             \
    }                                                                                \
  } while (0)

  for (int it = 0; it < NIT; ++it) {
    const int T = it << 1;
    TILE(0, T + 1, T + 2);
    TILE(1, T + 2, T + 3);
  }

  // epilogue: D frag layout row=(l>>4)*4+j, col=l&15 (verified R1-R3)
  const int orow = brow + (wr << 7) + ((l >> 4) << 2);
  const int ocol = bcol + (wc << 6) + lr;
  float bb[4];
#pragma unroll
  for (int n = 0; n < 4; ++n) bb[n] = bias[ocol + n * 16];
#pragma unroll
  for (int mi = 0; mi < 8; ++mi)
#pragma unroll
    for (int n = 0; n < 4; ++n)
#pragma unroll
      for (int j = 0; j < 4; ++j)
        out[(size_t)(orow + mi * 16 + j) * N + ocol + n * 16] = acc[mi][n][j] + bb[n];
}

extern "C" void kernel_launch(void* const* d_in, const int* in_sizes, int n_in,
                              void* d_out, int out_size, void* d_ws, size_t ws_size,
                              hipStream_t stream) {
  const float* x    = (const float*)d_in[0];
  const float* wgt  = (const float*)d_in[1];
  const float* bias = (const float*)d_in[2];
  const float* Abuf = (const float*)d_in[3];
  const float* Bbuf = (const float*)d_in[4];
  const int*   aid  = (const int*)d_in[5];
  float* out = (float*)d_out;

  // workspace: Xaug[8192][4608] | Waug[4096][4608] | Abf[512][4096]  (bf16 as ushort)
  ushort_t* Xaug = (ushort_t*)d_ws;
  ushort_t* Waug = Xaug + (size_t)NUM_TOKENS * KAUG;
  ushort_t* Abf  = Waug + (size_t)OUT_DIM * KAUG;

  // merged conversions: pad (x + wgt), small (A-flat + B-scatter)
  k_cvt_pad2<<<(XTHREADS + OUT_DIM * IN_DIM / 4) / 256, 256, 0, stream>>>(x, wgt, Xaug, Waug);
  k_cvt_small<<<(FTHREADS + NUM_AD * OUT_DIM * RANK / 4) / 256, 256, 0, stream>>>(
      Abuf, Bbuf, Abf, Waug);

  // Z = mask(X @ A_flat^T) into Xaug cols 4096..4607: M=8192 N=512 K=4096
  gemm_lora_a<<<(NUM_TOKENS / 128) * (RTOT / 64), 256, 0, stream>>>(Xaug, Abf, Xaug, aid);

  // out = Xaug @ Waug^T + bias: M=8192 N=4096 K=4608 (72 K-tiles, 36 iters)
  gemm8<<<(NUM_TOKENS / 256) * (OUT_DIM / 256), 512, 131072, stream>>>(
      Xaug, KAUG, Waug, KAUG, NUM_TOKENS, OUT_DIM, KAUG, out, bias);
}